// Round 3
// baseline (105.145 us; speedup 1.0000x reference)
//
#include <hip/hip_runtime.h>
#include <math.h>

#define B_   16
#define N_   256
#define F_   64
#define FP_  16
#define H_   128
#define T_   192                   // LUT entries: 192*64*4 = 48 KB (LDS-resident)
#define I_   2                     // i-rows per block
#define DMAX 1.7320508075688772f   // sqrt(3): r in [0,1]^3

__device__ __forceinline__ float sp(float x) {
    // numerically stable softplus: max(x,0) + log1p(exp(-|x|))
    return fmaxf(x, 0.0f) + log1pf(expf(-fabsf(x)));
}

// -------- Kernel 1: tabulate d -> softplus(MLP(d)) into lut[T_][F_] --------
// grid = T_ blocks, 128 threads
__global__ void pp_build_lut(const float* __restrict__ mp_w1,
                             const float* __restrict__ mp_b1,
                             const float* __restrict__ mp_w2,
                             const float* __restrict__ mp_b2,
                             float* __restrict__ lut, float dstep) {
    __shared__ float hid[H_];
    const int t   = blockIdx.x;
    const int tid = threadIdx.x;
    const float d = t * dstep;
    hid[tid] = sp(fmaf(d, mp_w1[tid], mp_b1[tid]));   // tid in [0,128)
    __syncthreads();
    if (tid < F_) {
        float z = mp_b2[tid];
        #pragma unroll 8
        for (int h = 0; h < H_; ++h)
            z = fmaf(hid[h], mp_w2[h * F_ + tid], z);
        lut[(size_t)t * F_ + tid] = sp(z);
    }
}

// -------- Kernel 2: LDS-resident LUT, 2 rows per block, 2048 blocks -------
// grid = B_*N_/I_ = 2048 blocks, 256 threads
__global__ __launch_bounds__(256) void pp_predict(
        const float* __restrict__ r,   const float* __restrict__ fb,
        const float* __restrict__ lut,
        const float* __restrict__ pc_w1, const float* __restrict__ pc_b1,
        const float* __restrict__ pc_w2, const float* __restrict__ pc_b2,
        float* __restrict__ out, float inv_step) {
    const int tid   = threadIdx.x;
    const int b     = blockIdx.x >> 7;               // 128 blocks per batch
    const int itile = (blockIdx.x & 127) * I_;       // first of 2 i-rows

    __shared__ float s_lut[T_ * F_];     // 48 KB
    __shared__ float s_scr[I_ * N_];     // 2 KB: fi -> partials -> h2 (barrier-sequenced)
    __shared__ float s_fbar[I_ * F_];    // 512 B

    // ---- distances for the 2 rows (writes s_scr) ----
    {
        const int j = tid;
        const float xj = r[(b * N_ + j) * 3 + 0];
        const float yj = r[(b * N_ + j) * 3 + 1];
        const float zj = r[(b * N_ + j) * 3 + 2];
        #pragma unroll
        for (int ii = 0; ii < I_; ++ii) {
            const int i = itile + ii;
            const float dx = r[(b * N_ + i) * 3 + 0] - xj;
            const float dy = r[(b * N_ + i) * 3 + 1] - yj;
            const float dz = r[(b * N_ + i) * 3 + 2] - zj;
            const float sq = fmaf(dx, dx, fmaf(dy, dy, dz * dz));
            const float d  = sq > 0.0f ? sqrtf(sq) : 0.0f;
            // clamp so (int)fi <= T_-2 and frac stays in [0,1)
            s_scr[ii * N_ + j] = fminf(d * inv_step, (float)(T_ - 1) - 1e-3f);
        }
    }

    // ---- stage LUT into LDS (12288 floats / 256 thr = 12 x float4) ----
    {
        const float4* src = (const float4*)lut;
        float4*       dst = (float4*)s_lut;
        #pragma unroll
        for (int k = 0; k < (T_ * F_ / 4) / 256; ++k)
            dst[k * 256 + tid] = src[k * 256 + tid];
    }
    __syncthreads();

    // ---- cache this thread's 32 fi values in VGPRs ----
    const int fq = tid & 15;     // float4 group within the 64-f row
    const int jg = tid >> 4;     // 16 groups of 16 j
    float fi_reg[I_][16];
    #pragma unroll
    for (int ii = 0; ii < I_; ++ii)
        #pragma unroll
        for (int jj = 0; jj < 16; ++jj)
            fi_reg[ii][jj] = s_scr[ii * N_ + jg * 16 + jj];
    __syncthreads();   // all fi consumed into regs; s_scr reusable after main loop

    // ---- main loop: acc[ii][f4] += lerp(lut, d_{i,j}) * fb[b,j,f4] ----
    float4 acc[I_];
    #pragma unroll
    for (int ii = 0; ii < I_; ++ii) acc[ii] = make_float4(0.f, 0.f, 0.f, 0.f);

    const float* fbrow = fb + (size_t)b * N_ * F_ + fq * 4;
    float4 fv = *(const float4*)(fbrow + (jg * 16) * F_);
    #pragma unroll
    for (int jj = 0; jj < 16; ++jj) {
        float4 fv_n = fv;
        if (jj < 15) fv_n = *(const float4*)(fbrow + (jg * 16 + jj + 1) * F_);
        #pragma unroll
        for (int ii = 0; ii < I_; ++ii) {
            const float fi  = fi_reg[ii][jj];
            const int   idx = (int)fi;
            const float frac = fi - (float)idx;
            const float* p0 = s_lut + idx * F_ + fq * 4;
            const float4 L0 = *(const float4*)(p0);
            const float4 L1 = *(const float4*)(p0 + F_);
            acc[ii].x = fmaf(fmaf(frac, L1.x - L0.x, L0.x), fv.x, acc[ii].x);
            acc[ii].y = fmaf(fmaf(frac, L1.y - L0.y, L0.y), fv.y, acc[ii].y);
            acc[ii].z = fmaf(fmaf(frac, L1.z - L0.z, L0.z), fv.z, acc[ii].z);
            acc[ii].w = fmaf(fmaf(frac, L1.w - L0.w, L0.w), fv.w, acc[ii].w);
        }
        fv = fv_n;
    }

    // ---- reduce 16 j-groups: shfl across quarters, 4 wave-partials in LDS ----
    #pragma unroll
    for (int ii = 0; ii < I_; ++ii) {
        acc[ii].x += __shfl_xor(acc[ii].x, 16); acc[ii].y += __shfl_xor(acc[ii].y, 16);
        acc[ii].z += __shfl_xor(acc[ii].z, 16); acc[ii].w += __shfl_xor(acc[ii].w, 16);
        acc[ii].x += __shfl_xor(acc[ii].x, 32); acc[ii].y += __shfl_xor(acc[ii].y, 32);
        acc[ii].z += __shfl_xor(acc[ii].z, 32); acc[ii].w += __shfl_xor(acc[ii].w, 32);
    }
    const int wv = tid >> 6;             // wave id 0..3
    if ((tid & 63) < 16) {
        #pragma unroll
        for (int ii = 0; ii < I_; ++ii)
            *(float4*)(s_scr + ii * N_ + wv * F_ + fq * 4) = acc[ii];
    }
    __syncthreads();

    // ---- f_bar = sp(sum of 4 wave-partials) : 128 items = 2 ii x 64 f ----
    if (tid < I_ * F_) {
        const int ii = tid >> 6, f = tid & 63;
        float s = s_scr[ii * N_ + 0 * F_ + f] + s_scr[ii * N_ + 1 * F_ + f]
                + s_scr[ii * N_ + 2 * F_ + f] + s_scr[ii * N_ + 3 * F_ + f];
        s_fbar[ii * F_ + f] = sp(s);
    }
    __syncthreads();   // s_scr (partials) dead; reuse as h2 buffer

    // ---- h2[ii][h] = sp(fbar . pc_w1[:,h] + b1[h]) : 256 items ----
    {
        const int ii = tid >> 7, h = tid & 127;
        float z = pc_b1[h];
        #pragma unroll 8
        for (int f = 0; f < F_; ++f)
            z = fmaf(s_fbar[ii * F_ + f], pc_w1[f * H_ + h], z);
        s_scr[ii * H_ + h] = sp(z);
    }
    __syncthreads();

    // ---- out[ii][p] = sp(h2 . pc_w2[:,p] + b2[p]) : 32 items ----
    if (tid < I_ * FP_) {
        const int ii = tid >> 4, p = tid & 15;
        float z = pc_b2[p];
        #pragma unroll 8
        for (int h = 0; h < H_; ++h)
            z = fmaf(s_scr[ii * H_ + h], pc_w2[h * FP_ + p], z);
        out[((size_t)(b * N_ + itile + ii)) * FP_ + p] = sp(z);
    }
}

extern "C" void kernel_launch(void* const* d_in, const int* in_sizes, int n_in,
                              void* d_out, int out_size, void* d_ws, size_t ws_size,
                              hipStream_t stream) {
    const float* r_batch = (const float*)d_in[0];
    const float* f_batch = (const float*)d_in[1];
    const float* mp_w1   = (const float*)d_in[2];
    const float* mp_b1   = (const float*)d_in[3];
    const float* mp_w2   = (const float*)d_in[4];
    const float* mp_b2   = (const float*)d_in[5];
    const float* pc_w1   = (const float*)d_in[6];
    const float* pc_b1   = (const float*)d_in[7];
    const float* pc_w2   = (const float*)d_in[8];
    const float* pc_b2   = (const float*)d_in[9];
    float* out = (float*)d_out;
    float* lut = (float*)d_ws;   // T_*F_*4 = 48 KB scratch

    const float dstep    = DMAX / (float)(T_ - 1);
    const float inv_step = (float)(T_ - 1) / DMAX;

    pp_build_lut<<<T_, H_, 0, stream>>>(mp_w1, mp_b1, mp_w2, mp_b2, lut, dstep);
    pp_predict<<<B_ * N_ / I_, 256, 0, stream>>>(r_batch, f_batch, lut,
                                                 pc_w1, pc_b1, pc_w2, pc_b2,
                                                 out, inv_step);
}

// Round 4
// 102.441 us; speedup vs baseline: 1.0264x; 1.0264x over previous
//
#include <hip/hip_runtime.h>
#include <math.h>

#define B_   16
#define N_   256
#define F_   64
#define FP_  16
#define H_   128
#define T_   256                   // LUT entries: 256*64*2B = 32 KB (fp16, LDS-resident)
#define I_   2                     // i-rows per block
#define DMAX 1.7320508075688772f   // sqrt(3): r in [0,1]^3

typedef _Float16 half_t;
typedef __attribute__((ext_vector_type(4))) _Float16 half4;

__device__ __forceinline__ float sp(float x) {
    // numerically stable softplus: max(x,0) + log1p(exp(-|x|))
    return fmaxf(x, 0.0f) + log1pf(expf(-fabsf(x)));
}

// -------- Kernel 1: tabulate d -> softplus(MLP(d)) into fp16 lut[T_][F_] --
// grid = T_ blocks, 128 threads
__global__ void pp_build_lut(const float* __restrict__ mp_w1,
                             const float* __restrict__ mp_b1,
                             const float* __restrict__ mp_w2,
                             const float* __restrict__ mp_b2,
                             half_t* __restrict__ lut, float dstep) {
    __shared__ float hid[H_];
    const int t   = blockIdx.x;
    const int tid = threadIdx.x;
    const float d = t * dstep;
    hid[tid] = sp(fmaf(d, mp_w1[tid], mp_b1[tid]));   // tid in [0,128)
    __syncthreads();
    if (tid < F_) {
        float z = mp_b2[tid];
        #pragma unroll 8
        for (int h = 0; h < H_; ++h)
            z = fmaf(hid[h], mp_w2[h * F_ + tid], z);
        lut[(size_t)t * F_ + tid] = (half_t)sp(z);
    }
}

// -------- Kernel 2: fp16 LDS LUT, 2 rows/block, depth-4 fv prefetch -------
// grid = B_*N_/I_ = 2048 blocks, 256 threads
__global__ __launch_bounds__(256, 4) void pp_predict(
        const float* __restrict__ r,   const float* __restrict__ fb,
        const half_t* __restrict__ lut,
        const float* __restrict__ pc_w1, const float* __restrict__ pc_b1,
        const float* __restrict__ pc_w2, const float* __restrict__ pc_b2,
        float* __restrict__ out, float inv_step) {
    const int tid   = threadIdx.x;
    const int b     = blockIdx.x >> 7;               // 128 blocks per batch
    const int itile = (blockIdx.x & 127) * I_;       // first of 2 i-rows

    __shared__ half_t s_lut[T_ * F_];    // 32 KB
    __shared__ float  s_scr[I_ * N_];    // 2 KB: fi -> partials -> h2 (barrier-sequenced)
    __shared__ float  s_fbar[I_ * F_];   // 512 B

    // ---- distances for the 2 rows (writes s_scr) ----
    {
        const int j = tid;
        const float xj = r[(b * N_ + j) * 3 + 0];
        const float yj = r[(b * N_ + j) * 3 + 1];
        const float zj = r[(b * N_ + j) * 3 + 2];
        #pragma unroll
        for (int ii = 0; ii < I_; ++ii) {
            const int i = itile + ii;
            const float dx = r[(b * N_ + i) * 3 + 0] - xj;
            const float dy = r[(b * N_ + i) * 3 + 1] - yj;
            const float dz = r[(b * N_ + i) * 3 + 2] - zj;
            const float sq = fmaf(dx, dx, fmaf(dy, dy, dz * dz));
            const float d  = sq > 0.0f ? sqrtf(sq) : 0.0f;
            // clamp so (int)fi <= T_-2 and frac stays in [0,1)
            s_scr[ii * N_ + j] = fminf(d * inv_step, (float)(T_ - 1) - 1e-3f);
        }
    }

    // ---- stage fp16 LUT into LDS (32 KB = 8 x float4 per thread) ----
    {
        const float4* src = (const float4*)lut;
        float4*       dst = (float4*)s_lut;
        #pragma unroll
        for (int k = 0; k < (T_ * F_ * 2 / 16) / 256; ++k)
            dst[k * 256 + tid] = src[k * 256 + tid];
    }
    __syncthreads();

    // ---- cache this thread's 32 fi values in VGPRs ----
    const int fq = tid & 15;     // float4 group within the 64-f row
    const int jg = tid >> 4;     // 16 groups of 16 j
    float fi_reg[I_][16];
    #pragma unroll
    for (int ii = 0; ii < I_; ++ii)
        #pragma unroll
        for (int jj = 0; jj < 16; ++jj)
            fi_reg[ii][jj] = s_scr[ii * N_ + jg * 16 + jj];
    __syncthreads();   // all fi consumed into regs; s_scr reusable after main loop

    // ---- main loop: acc[ii][f4] += lerp(lut, d_{i,j}) * fb[b,j,f4] ----
    float4 acc[I_];
    #pragma unroll
    for (int ii = 0; ii < I_; ++ii) acc[ii] = make_float4(0.f, 0.f, 0.f, 0.f);

    const float* fbrow = fb + (size_t)b * N_ * F_ + fq * 4;
    float4 fvbuf[4];
    #pragma unroll
    for (int p = 0; p < 4; ++p)
        fvbuf[p] = *(const float4*)(fbrow + (jg * 16 + p) * F_);

    #pragma unroll
    for (int jj = 0; jj < 16; ++jj) {
        const float4 fv = fvbuf[jj & 3];
        if (jj < 12)
            fvbuf[jj & 3] = *(const float4*)(fbrow + (jg * 16 + jj + 4) * F_);
        #pragma unroll
        for (int ii = 0; ii < I_; ++ii) {
            const float fi   = fi_reg[ii][jj];
            const int   idx  = (int)fi;
            const float frac = fi - (float)idx;
            const half4 L0 = *(const half4*)(s_lut + idx * F_ + fq * 4);
            const half4 L1 = *(const half4*)(s_lut + (idx + 1) * F_ + fq * 4);
            const float l0x = (float)L0.x, l1x = (float)L1.x;
            const float l0y = (float)L0.y, l1y = (float)L1.y;
            const float l0z = (float)L0.z, l1z = (float)L1.z;
            const float l0w = (float)L0.w, l1w = (float)L1.w;
            acc[ii].x = fmaf(fmaf(frac, l1x - l0x, l0x), fv.x, acc[ii].x);
            acc[ii].y = fmaf(fmaf(frac, l1y - l0y, l0y), fv.y, acc[ii].y);
            acc[ii].z = fmaf(fmaf(frac, l1z - l0z, l0z), fv.z, acc[ii].z);
            acc[ii].w = fmaf(fmaf(frac, l1w - l0w, l0w), fv.w, acc[ii].w);
        }
    }

    // ---- reduce 16 j-groups: shfl across quarters, 4 wave-partials in LDS ----
    #pragma unroll
    for (int ii = 0; ii < I_; ++ii) {
        acc[ii].x += __shfl_xor(acc[ii].x, 16); acc[ii].y += __shfl_xor(acc[ii].y, 16);
        acc[ii].z += __shfl_xor(acc[ii].z, 16); acc[ii].w += __shfl_xor(acc[ii].w, 16);
        acc[ii].x += __shfl_xor(acc[ii].x, 32); acc[ii].y += __shfl_xor(acc[ii].y, 32);
        acc[ii].z += __shfl_xor(acc[ii].z, 32); acc[ii].w += __shfl_xor(acc[ii].w, 32);
    }
    const int wv = tid >> 6;             // wave id 0..3
    if ((tid & 63) < 16) {
        #pragma unroll
        for (int ii = 0; ii < I_; ++ii)
            *(float4*)(s_scr + ii * N_ + wv * F_ + fq * 4) = acc[ii];
    }
    __syncthreads();

    // ---- f_bar = sp(sum of 4 wave-partials) : 128 items = 2 ii x 64 f ----
    if (tid < I_ * F_) {
        const int ii = tid >> 6, f = tid & 63;
        float s = s_scr[ii * N_ + 0 * F_ + f] + s_scr[ii * N_ + 1 * F_ + f]
                + s_scr[ii * N_ + 2 * F_ + f] + s_scr[ii * N_ + 3 * F_ + f];
        s_fbar[ii * F_ + f] = sp(s);
    }
    __syncthreads();   // s_scr (partials) dead; reuse as h2 buffer

    // ---- h2[ii][h] = sp(fbar . pc_w1[:,h] + b1[h]) : 256 items ----
    {
        const int ii = tid >> 7, h = tid & 127;
        float z = pc_b1[h];
        #pragma unroll 8
        for (int f = 0; f < F_; ++f)
            z = fmaf(s_fbar[ii * F_ + f], pc_w1[f * H_ + h], z);
        s_scr[ii * H_ + h] = sp(z);
    }
    __syncthreads();

    // ---- out[ii][p] = sp(h2 . pc_w2[:,p] + b2[p]) : 32 items ----
    if (tid < I_ * FP_) {
        const int ii = tid >> 4, p = tid & 15;
        float z = pc_b2[p];
        #pragma unroll 8
        for (int h = 0; h < H_; ++h)
            z = fmaf(s_scr[ii * H_ + h], pc_w2[h * FP_ + p], z);
        out[((size_t)(b * N_ + itile + ii)) * FP_ + p] = sp(z);
    }
}

extern "C" void kernel_launch(void* const* d_in, const int* in_sizes, int n_in,
                              void* d_out, int out_size, void* d_ws, size_t ws_size,
                              hipStream_t stream) {
    const float* r_batch = (const float*)d_in[0];
    const float* f_batch = (const float*)d_in[1];
    const float* mp_w1   = (const float*)d_in[2];
    const float* mp_b1   = (const float*)d_in[3];
    const float* mp_w2   = (const float*)d_in[4];
    const float* mp_b2   = (const float*)d_in[5];
    const float* pc_w1   = (const float*)d_in[6];
    const float* pc_b1   = (const float*)d_in[7];
    const float* pc_w2   = (const float*)d_in[8];
    const float* pc_b2   = (const float*)d_in[9];
    float* out = (float*)d_out;
    half_t* lut = (half_t*)d_ws;   // T_*F_*2 = 32 KB scratch

    const float dstep    = DMAX / (float)(T_ - 1);
    const float inv_step = (float)(T_ - 1) / DMAX;

    pp_build_lut<<<T_, H_, 0, stream>>>(mp_w1, mp_b1, mp_w2, mp_b2, lut, dstep);
    pp_predict<<<B_ * N_ / I_, 256, 0, stream>>>(r_batch, f_batch, lut,
                                                 pc_w1, pc_b1, pc_w2, pc_b2,
                                                 out, inv_step);
}